// Round 5
// baseline (318.897 us; speedup 1.0000x reference)
//
#include <hip/hip_runtime.h>
#include <hip/hip_bf16.h>
#include <math.h>

typedef __hip_bfloat16  bf16_t;
typedef __attribute__((ext_vector_type(8))) short  short8;   // 8 bf16 (4 VGPRs)
typedef __attribute__((ext_vector_type(4))) float  f32x4;
typedef __attribute__((ext_vector_type(4))) int    intv4;    // for nontemporal int4 loads

#define CDIM 128
#define KCAP 32            // fixed CSR slots per node; overflow -> exact spill list

static __device__ __forceinline__ float sigm(float x){ return 1.0f/(1.0f+__expf(-x)); }
static __device__ __forceinline__ float bflo(unsigned u){ return __builtin_bit_cast(float, u << 16); }
static __device__ __forceinline__ float bfhi(unsigned u){ return __builtin_bit_cast(float, u & 0xffff0000u); }
static __device__ __forceinline__ unsigned short f2bf_u(float f){
    __hip_bfloat16 h = __float2bfloat16(f);
    return __builtin_bit_cast(unsigned short, h);
}
static __device__ __forceinline__ unsigned packbf(float a, float b){
    return (unsigned)f2bf_u(a) | ((unsigned)f2bf_u(b) << 16);
}
static __device__ __forceinline__ short f2bf_s(float f){
    return (short)f2bf_u(f);
}

// ---------- 1. LSTM single step -> w_new in MFMA B-frag layout; also zeroes deg/spillc ----------
// wfrag short index: ((t*8+n0)*64 + quad*16+mm)*8 + jj  <=>  B[k=32t+quad*8+jj][n=n0*16+mm]
__global__ void k_lstm(const float* __restrict__ weight, const float* __restrict__ w_ih,
                       const float* __restrict__ b_ih,   const float* __restrict__ b_hh,
                       short* __restrict__ wfrag, int* __restrict__ zptr, int zcount){
    // fold the memset dispatch: 16384 threads grid-stride zero deg+spillc (~100K ints)
    const int gtid = blockIdx.x*CDIM + threadIdx.x;
    for(int i = gtid; i < zcount; i += CDIM*CDIM) zptr[i] = 0;

    __shared__ float wrow[CDIM];
    const int r = blockIdx.x, j = threadIdx.x;
    wrow[j] = weight[r*CDIM + j];
    __syncthreads();
    const float4* wi = (const float4*)(w_ih + (size_t)j*CDIM);
    const float4* wg = (const float4*)(w_ih + (size_t)(2*CDIM + j)*CDIM);
    const float4* wo = (const float4*)(w_ih + (size_t)(3*CDIM + j)*CDIM);
    const float4* wr = (const float4*)wrow;
    float si = 0.f, sg = 0.f, so = 0.f;
    #pragma unroll 8
    for(int k = 0; k < CDIM/4; k++){
        float4 w4 = wr[k];
        float4 a = wi[k]; si += w4.x*a.x + w4.y*a.y + w4.z*a.z + w4.w*a.w;
        float4 b = wg[k]; sg += w4.x*b.x + w4.y*b.y + w4.z*b.z + w4.w*b.w;
        float4 c = wo[k]; so += w4.x*c.x + w4.y*c.y + w4.z*c.z + w4.w*c.w;
    }
    si += b_ih[j]        + b_hh[j];
    sg += b_ih[2*CDIM+j] + b_hh[2*CDIM+j];
    so += b_ih[3*CDIM+j] + b_hh[3*CDIM+j];
    float c  = sigm(si)*tanhf(sg);           // f-gate * c0 = 0
    float wv = sigm(so)*tanhf(c);
    const int t = r >> 5, quad = (r >> 3) & 3, jj = r & 7;   // uniform per block
    const int n0 = j >> 4, mm = j & 15;
    wfrag[((size_t)((t*8 + n0)*64 + quad*16 + mm))*8 + jj] = f2bf_s(wv);
}

// ---------- 2. fused graph build: padded CSR (KCAP slots/node) in ONE edge pass ----------
// XCD-partitioned by dst range (blockIdx&7 -> round-robin XCD): cnt atomics and csr
// writes stay in ONE L2. NT int4 loads keep the edge stream from evicting csr lines.
// KEY CHANGE (R5): batch 8 elements per iteration -- issue ALL 8 atomicAdds (results
// parked in pv[]) BEFORE any dependent csr store. vmcnt completes in-order, so stores
// drain as vmcnt(7..0): 8 overlapping atomic latencies per wave instead of ~1.
__global__ __launch_bounds__(256) void k_fillfix(const int* __restrict__ src, const int* __restrict__ dst,
        int e, int* __restrict__ cnt, int* __restrict__ csr,
        int2* __restrict__ spill, int* __restrict__ spillc, int nper){
    const int grp = blockIdx.x & 7;
    const int lo  = grp*nper, hi = lo + nper;
    const int tid = (blockIdx.x >> 3)*256 + threadIdx.x;
    const int nt  = (gridDim.x >> 3)*256;
    const int e4  = e >> 2;
    const intv4* d4 = (const intv4*)dst;
    const intv4* s4 = (const intv4*)src;
    int i = tid;
    for(; i + nt < e4; i += 2*nt){
        intv4 da = __builtin_nontemporal_load(d4 + i);
        intv4 db = __builtin_nontemporal_load(d4 + i + nt);
        intv4 sa = __builtin_nontemporal_load(s4 + i);
        intv4 sb = __builtin_nontemporal_load(s4 + i + nt);
        int pv[8];
        #pragma unroll
        for(int c = 0; c < 4; c++){
            int di = da[c];
            pv[c] = (di >= lo && di < hi) ? atomicAdd(&cnt[di], 1) : -1;
        }
        #pragma unroll
        for(int c = 0; c < 4; c++){
            int di = db[c];
            pv[4+c] = (di >= lo && di < hi) ? atomicAdd(&cnt[di], 1) : -1;
        }
        #pragma unroll
        for(int c = 0; c < 4; c++){
            int p = pv[c];
            if(p >= 0){
                if(p < KCAP) csr[(size_t)da[c]*KCAP + p] = sa[c];
                else { int sp = atomicAdd(spillc, 1); spill[sp] = make_int2(sa[c], da[c]); }
            }
        }
        #pragma unroll
        for(int c = 0; c < 4; c++){
            int p = pv[4+c];
            if(p >= 0){
                if(p < KCAP) csr[(size_t)db[c]*KCAP + p] = sb[c];
                else { int sp = atomicAdd(spillc, 1); spill[sp] = make_int2(sb[c], db[c]); }
            }
        }
    }
    for(; i < e4; i += nt){                    // leftover int4 tiles
        intv4 da = __builtin_nontemporal_load(d4 + i);
        intv4 sa = __builtin_nontemporal_load(s4 + i);
        int pv[4];
        #pragma unroll
        for(int c = 0; c < 4; c++){
            int di = da[c];
            pv[c] = (di >= lo && di < hi) ? atomicAdd(&cnt[di], 1) : -1;
        }
        #pragma unroll
        for(int c = 0; c < 4; c++){
            int p = pv[c];
            if(p >= 0){
                if(p < KCAP) csr[(size_t)da[c]*KCAP + p] = sa[c];
                else { int sp = atomicAdd(spillc, 1); spill[sp] = make_int2(sa[c], da[c]); }
            }
        }
    }
    for(int k = e4*4 + tid; k < e; k += nt){   // scalar tail (e % 4 elements)
        int di = dst[k];
        if(di >= lo && di < hi){
            int sv = src[k];
            int p = atomicAdd(&cnt[di], 1);
            if(p < KCAP) csr[(size_t)di*KCAP + p] = sv;
            else { int sp = atomicAdd(spillc, 1); spill[sp] = make_int2(sv, di); }
        }
    }
}

// ---------- 3. y = bf16(dinv .* x) for this block's 256 nodes (dinv from final cnt) ----------
__global__ __launch_bounds__(256) void k_offscale(const float* __restrict__ x,
        const int* __restrict__ deg, bf16_t* __restrict__ y, int n){
    __shared__ float sdinv[256];
    const int base = blockIdx.x*256;
    const int t = threadIdx.x;
    const int i = base + t;
    float dv = 0.f;
    if(i < n) dv = rsqrtf((float)(deg[i] + 1));     // +1 self-loop
    sdinv[t] = dv;
    __syncthreads();
    const int wid = t >> 6, lane = t & 63;
    for(int r = wid; r < 256; r += 4){
        int row = base + r;
        if(row >= n) break;
        float di = sdinv[r];
        float2 v = ((const float2*)(x + (size_t)row*CDIM))[lane];
        ((unsigned*)(y + (size_t)row*CDIM))[lane] = packbf(di*v.x, di*v.y);
    }
}

// ---------- 4. aggregate: agg[i] = bf16( dinv[i] * (y[i] + sum_{j in N(i)} y[j]) ) ----------
// One wave per node; quad q handles neighbors (4t+q). m <= KCAP = 32 -> FULLY UNROLLED:
// 8 guarded row-gathers per quad issued back-to-back -> 32 rows in flight per wave.
__global__ __launch_bounds__(256) void k_agg(const bf16_t* __restrict__ y, const int* __restrict__ csr,
                      const int* __restrict__ deg, const int2* __restrict__ spill,
                      const int* __restrict__ spillc, bf16_t* __restrict__ agg, int n){
    const int node = (int)(((size_t)blockIdx.x*256 + threadIdx.x) >> 6);
    if(node >= n) return;
    const int lane = threadIdx.x & 63;
    const int q = lane >> 4, f = lane & 15;
    const int   cnt = deg[node];
    const float di  = rsqrtf((float)(cnt + 1));
    const int   m   = cnt < KCAP ? cnt : KCAP;
    const uint4* yrow = (const uint4*)y;               // 16 uint4 per row
    uint4 sv = yrow[(size_t)node*16 + f];              // self row
    int jid = (lane < m) ? csr[(size_t)node*KCAP + lane] : 0;

    int jv[8];
    #pragma unroll
    for(int t = 0; t < 8; t++) jv[t] = __shfl(jid, 4*t + q, 64);

    uint4 v[8];
    #pragma unroll
    for(int t = 0; t < 8; t++)
        if(4*t + q < m) v[t] = yrow[(size_t)jv[t]*16 + f];   // all 8 issued before first use

    float acc[8];
    #pragma unroll
    for(int i = 0; i < 8; i++) acc[i] = 0.f;
    #pragma unroll
    for(int t = 0; t < 8; t++){
        if(4*t + q < m){
            acc[0] += bflo(v[t].x); acc[1] += bfhi(v[t].x);
            acc[2] += bflo(v[t].y); acc[3] += bfhi(v[t].y);
            acc[4] += bflo(v[t].z); acc[5] += bfhi(v[t].z);
            acc[6] += bflo(v[t].w); acc[7] += bfhi(v[t].w);
        }
    }
    // overflow edges (cold path: spillc == 0 for typical degree distributions)
    int sc = *spillc;
    if(sc > 0){
        for(int t = q; t < sc; t += 4){                // quads split the list; reduce below sums
            int2 sd = spill[t];
            if(sd.y == node){
                uint4 vv = yrow[(size_t)sd.x*16 + f];
                acc[0] += bflo(vv.x); acc[1] += bfhi(vv.x);
                acc[2] += bflo(vv.y); acc[3] += bfhi(vv.y);
                acc[4] += bflo(vv.z); acc[5] += bfhi(vv.z);
                acc[6] += bflo(vv.w); acc[7] += bfhi(vv.w);
            }
        }
    }
    #pragma unroll
    for(int i = 0; i < 8; i++){
        acc[i] += __shfl_xor(acc[i], 16, 64);
        acc[i] += __shfl_xor(acc[i], 32, 64);
    }
    if(q == 0){
        uint4 o;
        o.x = packbf(di*(acc[0] + bflo(sv.x)), di*(acc[1] + bfhi(sv.x)));
        o.y = packbf(di*(acc[2] + bflo(sv.y)), di*(acc[3] + bfhi(sv.y)));
        o.z = packbf(di*(acc[4] + bflo(sv.z)), di*(acc[5] + bfhi(sv.z)));
        o.w = packbf(di*(acc[6] + bflo(sv.w)), di*(acc[7] + bfhi(sv.w)));
        ((uint4*)agg)[(size_t)node*16 + f] = o;
    }
}

// ---------- 5. out = agg(bf16) @ W(bf16 frags) via MFMA, f32 out ----------
__global__ __launch_bounds__(256) void k_mgemm(const bf16_t* __restrict__ agg,
                                               const short* __restrict__ wfrag,
                                               float* __restrict__ out, int n){
    const int wid  = blockIdx.x*4 + (threadIdx.x >> 6);   // one wave per 16-row stripe
    const int row0 = wid*16;
    if(row0 >= n) return;
    const int lane = threadIdx.x & 63;
    const int m    = lane & 15, quad = lane >> 4;
    int arow = row0 + m; if(arow > n-1) arow = n-1;
    const short* ap = (const short*)agg + (size_t)arow*CDIM + quad*8;
    short8 a0 = *(const short8*)(ap);
    short8 a1 = *(const short8*)(ap + 32);
    short8 a2 = *(const short8*)(ap + 64);
    short8 a3 = *(const short8*)(ap + 96);
    const short8* bp = (const short8*)wfrag;
    float* orow = out + (size_t)(row0 + quad*4)*CDIM + m;
    const bool full = (row0 + 16 <= n);
    #pragma unroll
    for(int n0 = 0; n0 < 8; n0++){
        f32x4 acc = {0.f, 0.f, 0.f, 0.f};
        acc = __builtin_amdgcn_mfma_f32_16x16x32_bf16(a0, bp[(0*8+n0)*64 + lane], acc, 0, 0, 0);
        acc = __builtin_amdgcn_mfma_f32_16x16x32_bf16(a1, bp[(1*8+n0)*64 + lane], acc, 0, 0, 0);
        acc = __builtin_amdgcn_mfma_f32_16x16x32_bf16(a2, bp[(2*8+n0)*64 + lane], acc, 0, 0, 0);
        acc = __builtin_amdgcn_mfma_f32_16x16x32_bf16(a3, bp[(3*8+n0)*64 + lane], acc, 0, 0, 0);
        if(full){
            #pragma unroll
            for(int r = 0; r < 4; r++)
                orow[(size_t)r*CDIM + n0*16] = acc[r];
        } else {
            #pragma unroll
            for(int r = 0; r < 4; r++)
                if(row0 + quad*4 + r < n) orow[(size_t)r*CDIM + n0*16] = acc[r];
        }
    }
}

extern "C" void kernel_launch(void* const* d_in, const int* in_sizes, int n_in,
                              void* d_out, int out_size, void* d_ws, size_t ws_size,
                              hipStream_t stream){
    const float* x      = (const float*)d_in[0];
    const int*   ei     = (const int*)  d_in[1];
    const float* weight = (const float*)d_in[2];
    const float* w_ih   = (const float*)d_in[3];
    // d_in[4] = w_hh: zero forward contribution (h0 = 0)
    const float* b_ih   = (const float*)d_in[5];
    const float* b_hh   = (const float*)d_in[6];
    float* out = (float*)d_out;

    const int n = in_sizes[0]/CDIM;   // 100000
    const int e = in_sizes[1]/2;      // 1600000
    const int* srcp = ei;
    const int* dstp = ei + e;

    auto alignup = [](size_t v){ return (v + 255) & ~(size_t)255; };
    char*  base = (char*)d_ws;
    size_t o = 0;
    short*  wfrag  = (short*) (base+o); o += alignup((size_t)CDIM*CDIM*sizeof(short));
    int*    deg    = (int*)   (base+o); o += alignup((size_t)n*4);          // | contiguous
    int*    spillc = (int*)   (base+o); o += alignup(256);                  // | zero region
    size_t  zbytes = (size_t)((char*)(base+o) - (char*)deg);
    int*    csr    = (int*)   (base+o); o += alignup((size_t)n*KCAP*4);     // 12.8 MB padded CSR
    bf16_t* aggbuf = (bf16_t*)(base+o); // n*CDIM*2 bytes  (~38.9 MB total: proven in R2)

    // d_out (51.2 MB) doubles as scratch until k_mgemm overwrites it last:
    //   [0, 25.6 MB)  : y = bf16(dinv .* x)
    //   [25.6, 38.4)  : spill list (int2, capacity e) -- normally empty
    bf16_t* y     = (bf16_t*)d_out;
    int2*   spill = (int2*)((char*)d_out + (size_t)n*CDIM*sizeof(bf16_t));

    const int nper = (n + 7)/8;               // dst-range per XCD group
    const int pb = 2048;                      // 256 blocks per group
    const int nb = (n + 255)/256;
    const int rb = (n + 3)/4;                 // k_agg: 4 waves (nodes) per block
    const int gw = (n + 15)/16;               // k_mgemm: 16-row stripes
    const int gb = (gw + 3)/4;

    k_lstm    <<<CDIM, CDIM, 0, stream>>>(weight, w_ih, b_ih, b_hh, wfrag,
                                          deg, (int)(zbytes/4));   // also zeroes deg+spillc
    k_fillfix <<<pb, 256, 0, stream>>>(srcp, dstp, e, deg, csr, spill, spillc, nper);
    k_offscale<<<nb, 256, 0, stream>>>(x, deg, y, n);
    k_agg     <<<rb, 256, 0, stream>>>(y, csr, deg, spill, spillc, aggbuf, n);
    k_mgemm   <<<gb, 256, 0, stream>>>(aggbuf, wfrag, out, n);
}

// Round 6
// 276.821 us; speedup vs baseline: 1.1520x; 1.1520x over previous
//
#include <hip/hip_runtime.h>
#include <hip/hip_bf16.h>
#include <math.h>

typedef __hip_bfloat16  bf16_t;
typedef __attribute__((ext_vector_type(8))) short  short8;   // 8 bf16 (4 VGPRs)
typedef __attribute__((ext_vector_type(4))) float  f32x4;
typedef __attribute__((ext_vector_type(4))) int    intv4;    // for nontemporal int4 loads

#define CDIM 128
#define KCAP 32            // fixed CSR slots per node; overflow -> exact spill list

static __device__ __forceinline__ float sigm(float x){ return 1.0f/(1.0f+__expf(-x)); }
static __device__ __forceinline__ float bflo(unsigned u){ return __builtin_bit_cast(float, u << 16); }
static __device__ __forceinline__ float bfhi(unsigned u){ return __builtin_bit_cast(float, u & 0xffff0000u); }
static __device__ __forceinline__ unsigned short f2bf_u(float f){
    __hip_bfloat16 h = __float2bfloat16(f);
    return __builtin_bit_cast(unsigned short, h);
}
static __device__ __forceinline__ unsigned packbf(float a, float b){
    return (unsigned)f2bf_u(a) | ((unsigned)f2bf_u(b) << 16);
}
static __device__ __forceinline__ short f2bf_s(float f){
    return (short)f2bf_u(f);
}

// ---------- 1. LSTM single step -> w_new in MFMA B-frag layout; also zeroes deg/spillc ----------
// wfrag short index: ((t*8+n0)*64 + quad*16+mm)*8 + jj  <=>  B[k=32t+quad*8+jj][n=n0*16+mm]
__global__ void k_lstm(const float* __restrict__ weight, const float* __restrict__ w_ih,
                       const float* __restrict__ b_ih,   const float* __restrict__ b_hh,
                       short* __restrict__ wfrag, int* __restrict__ zptr, int zcount){
    // fold the memset dispatch: 16384 threads grid-stride zero deg+spillc (~100K ints)
    const int gtid = blockIdx.x*CDIM + threadIdx.x;
    for(int i = gtid; i < zcount; i += CDIM*CDIM) zptr[i] = 0;

    __shared__ float wrow[CDIM];
    const int r = blockIdx.x, j = threadIdx.x;
    wrow[j] = weight[r*CDIM + j];
    __syncthreads();
    const float4* wi = (const float4*)(w_ih + (size_t)j*CDIM);
    const float4* wg = (const float4*)(w_ih + (size_t)(2*CDIM + j)*CDIM);
    const float4* wo = (const float4*)(w_ih + (size_t)(3*CDIM + j)*CDIM);
    const float4* wr = (const float4*)wrow;
    float si = 0.f, sg = 0.f, so = 0.f;
    #pragma unroll 8
    for(int k = 0; k < CDIM/4; k++){
        float4 w4 = wr[k];
        float4 a = wi[k]; si += w4.x*a.x + w4.y*a.y + w4.z*a.z + w4.w*a.w;
        float4 b = wg[k]; sg += w4.x*b.x + w4.y*b.y + w4.z*b.z + w4.w*b.w;
        float4 c = wo[k]; so += w4.x*c.x + w4.y*c.y + w4.z*c.z + w4.w*c.w;
    }
    si += b_ih[j]        + b_hh[j];
    sg += b_ih[2*CDIM+j] + b_hh[2*CDIM+j];
    so += b_ih[3*CDIM+j] + b_hh[3*CDIM+j];
    float c  = sigm(si)*tanhf(sg);           // f-gate * c0 = 0
    float wv = sigm(so)*tanhf(c);
    const int t = r >> 5, quad = (r >> 3) & 3, jj = r & 7;   // uniform per block
    const int n0 = j >> 4, mm = j & 15;
    wfrag[((size_t)((t*8 + n0)*64 + quad*16 + mm))*8 + jj] = f2bf_s(wv);
}

// ---------- 2. FUSED: graph build (atomic wall) + y0 = bf16(x) cast ----------
// The per-edge device atomic runs at a fixed ~21 G/s memory-side ceiling (R0/R2/R4/R5
// all pinned at ~75us) and leaves VALU ~5% / HBM ~19% idle. So the x->bf16 cast rides
// along as separate cast-blocks: 512 cast + 1536 edge = 2048 blocks, ALL co-resident
// (8 blocks/CU). Cast waves stream at full BW while edge waves stall on atomics.
// y0 is UNSCALED bf16(x); dinv scaling moved into k_agg (deg is final only after here).
__global__ __launch_bounds__(256) void k_fillcast(const int* __restrict__ src, const int* __restrict__ dst,
        int e, int* __restrict__ cnt, int* __restrict__ csr,
        int2* __restrict__ spill, int* __restrict__ spillc, int nper,
        const float* __restrict__ x, bf16_t* __restrict__ y0, int nf4,
        int castblocks, int edgeblocks){
    if((int)blockIdx.x < castblocks){
        // ---- cast path: grid-stride float4 -> 4x bf16 ----
        const float4* xv = (const float4*)x;
        uint2* yv = (uint2*)y0;
        const int t0   = blockIdx.x*256 + threadIdx.x;
        const int step = castblocks*256;
        for(int i = t0; i < nf4; i += step){
            float4 v = xv[i];
            uint2 o; o.x = packbf(v.x, v.y); o.y = packbf(v.z, v.w);
            yv[i] = o;
        }
        return;
    }
    // ---- edge path (R4 structure: best measured) ----
    const int bid = (int)blockIdx.x - castblocks;
    const int grp = bid & 7;
    const int lo  = grp*nper, hi = lo + nper;
    const int tid = (bid >> 3)*256 + threadIdx.x;
    const int nt  = (edgeblocks >> 3)*256;
    const int e4  = e >> 2;
    const intv4* d4 = (const intv4*)dst;
    const intv4* s4 = (const intv4*)src;
    for(int i = tid; i < e4; i += nt){
        intv4 d = __builtin_nontemporal_load(d4 + i);
        intv4 s = __builtin_nontemporal_load(s4 + i);
        #pragma unroll
        for(int c = 0; c < 4; c++){
            int di = d[c];
            if(di >= lo && di < hi){
                int p = atomicAdd(&cnt[di], 1);
                if(p < KCAP) csr[(size_t)di*KCAP + p] = s[c];
                else { int sp = atomicAdd(spillc, 1); spill[sp] = make_int2(s[c], di); }
            }
        }
    }
    for(int k = e4*4 + tid; k < e; k += nt){   // scalar tail (e % 4 elements)
        int di = dst[k];
        if(di >= lo && di < hi){
            int sv = src[k];
            int p = atomicAdd(&cnt[di], 1);
            if(p < KCAP) csr[(size_t)di*KCAP + p] = sv;
            else { int sp = atomicAdd(spillc, 1); spill[sp] = make_int2(sv, di); }
        }
    }
}

// ---------- 3. aggregate: agg[i] = bf16( di * ( sum_j dinv_j*y0_j + di*y0_i ) ) ----------
// One wave per node; quad q handles neighbors (4t+q). m <= KCAP = 32 -> FULLY UNROLLED:
// 8 deg loads + 8 row-gathers per quad issued back-to-back -> 40 loads in flight/wave.
// dinv_j = rsqrt(deg[j]+1) computed inline (deg is L2/L3-resident; 16-lane broadcast).
__global__ __launch_bounds__(256) void k_agg(const bf16_t* __restrict__ y, const int* __restrict__ csr,
                      const int* __restrict__ deg, const int2* __restrict__ spill,
                      const int* __restrict__ spillc, bf16_t* __restrict__ agg, int n){
    const int node = (int)(((size_t)blockIdx.x*256 + threadIdx.x) >> 6);
    if(node >= n) return;
    const int lane = threadIdx.x & 63;
    const int q = lane >> 4, f = lane & 15;
    const int   cnt = deg[node];
    const float di  = rsqrtf((float)(cnt + 1));
    const int   m   = cnt < KCAP ? cnt : KCAP;
    const uint4* yrow = (const uint4*)y;               // 16 uint4 per row
    uint4 sv = yrow[(size_t)node*16 + f];              // self row (unscaled bf16)
    int jid = (lane < m) ? csr[(size_t)node*KCAP + lane] : 0;

    int jv[8];
    #pragma unroll
    for(int t = 0; t < 8; t++) jv[t] = __shfl(jid, 4*t + q, 64);

    int dgv[8];
    #pragma unroll
    for(int t = 0; t < 8; t++)
        if(4*t + q < m) dgv[t] = deg[jv[t]];                 // broadcast loads, issued first

    uint4 v[8];
    #pragma unroll
    for(int t = 0; t < 8; t++)
        if(4*t + q < m) v[t] = yrow[(size_t)jv[t]*16 + f];   // all rows in flight

    float acc[8];
    #pragma unroll
    for(int i = 0; i < 8; i++) acc[i] = 0.f;
    #pragma unroll
    for(int t = 0; t < 8; t++){
        if(4*t + q < m){
            float dj = rsqrtf((float)(dgv[t] + 1));
            acc[0] += dj*bflo(v[t].x); acc[1] += dj*bfhi(v[t].x);
            acc[2] += dj*bflo(v[t].y); acc[3] += dj*bfhi(v[t].y);
            acc[4] += dj*bflo(v[t].z); acc[5] += dj*bfhi(v[t].z);
            acc[6] += dj*bflo(v[t].w); acc[7] += dj*bfhi(v[t].w);
        }
    }
    // overflow edges (cold path: spillc == 0 for typical degree distributions)
    int sc = *spillc;
    if(sc > 0){
        for(int t = q; t < sc; t += 4){                // quads split the list; reduce below sums
            int2 sd = spill[t];
            if(sd.y == node){
                float dj = rsqrtf((float)(deg[sd.x] + 1));
                uint4 vv = yrow[(size_t)sd.x*16 + f];
                acc[0] += dj*bflo(vv.x); acc[1] += dj*bfhi(vv.x);
                acc[2] += dj*bflo(vv.y); acc[3] += dj*bfhi(vv.y);
                acc[4] += dj*bflo(vv.z); acc[5] += dj*bfhi(vv.z);
                acc[6] += dj*bflo(vv.w); acc[7] += dj*bfhi(vv.w);
            }
        }
    }
    #pragma unroll
    for(int i = 0; i < 8; i++){
        acc[i] += __shfl_xor(acc[i], 16, 64);
        acc[i] += __shfl_xor(acc[i], 32, 64);
    }
    if(q == 0){
        uint4 o;
        o.x = packbf(di*(acc[0] + di*bflo(sv.x)), di*(acc[1] + di*bfhi(sv.x)));
        o.y = packbf(di*(acc[2] + di*bflo(sv.y)), di*(acc[3] + di*bfhi(sv.y)));
        o.z = packbf(di*(acc[4] + di*bflo(sv.z)), di*(acc[5] + di*bfhi(sv.z)));
        o.w = packbf(di*(acc[6] + di*bflo(sv.w)), di*(acc[7] + di*bfhi(sv.w)));
        ((uint4*)agg)[(size_t)node*16 + f] = o;
    }
}

// ---------- 4. out = agg(bf16) @ W(bf16 frags) via MFMA, f32 out ----------
__global__ __launch_bounds__(256) void k_mgemm(const bf16_t* __restrict__ agg,
                                               const short* __restrict__ wfrag,
                                               float* __restrict__ out, int n){
    const int wid  = blockIdx.x*4 + (threadIdx.x >> 6);   // one wave per 16-row stripe
    const int row0 = wid*16;
    if(row0 >= n) return;
    const int lane = threadIdx.x & 63;
    const int m    = lane & 15, quad = lane >> 4;
    int arow = row0 + m; if(arow > n-1) arow = n-1;
    const short* ap = (const short*)agg + (size_t)arow*CDIM + quad*8;
    short8 a0 = *(const short8*)(ap);
    short8 a1 = *(const short8*)(ap + 32);
    short8 a2 = *(const short8*)(ap + 64);
    short8 a3 = *(const short8*)(ap + 96);
    const short8* bp = (const short8*)wfrag;
    float* orow = out + (size_t)(row0 + quad*4)*CDIM + m;
    const bool full = (row0 + 16 <= n);
    #pragma unroll
    for(int n0 = 0; n0 < 8; n0++){
        f32x4 acc = {0.f, 0.f, 0.f, 0.f};
        acc = __builtin_amdgcn_mfma_f32_16x16x32_bf16(a0, bp[(0*8+n0)*64 + lane], acc, 0, 0, 0);
        acc = __builtin_amdgcn_mfma_f32_16x16x32_bf16(a1, bp[(1*8+n0)*64 + lane], acc, 0, 0, 0);
        acc = __builtin_amdgcn_mfma_f32_16x16x32_bf16(a2, bp[(2*8+n0)*64 + lane], acc, 0, 0, 0);
        acc = __builtin_amdgcn_mfma_f32_16x16x32_bf16(a3, bp[(3*8+n0)*64 + lane], acc, 0, 0, 0);
        if(full){
            #pragma unroll
            for(int r = 0; r < 4; r++)
                orow[(size_t)r*CDIM + n0*16] = acc[r];
        } else {
            #pragma unroll
            for(int r = 0; r < 4; r++)
                if(row0 + quad*4 + r < n) orow[(size_t)r*CDIM + n0*16] = acc[r];
        }
    }
}

extern "C" void kernel_launch(void* const* d_in, const int* in_sizes, int n_in,
                              void* d_out, int out_size, void* d_ws, size_t ws_size,
                              hipStream_t stream){
    const float* x      = (const float*)d_in[0];
    const int*   ei     = (const int*)  d_in[1];
    const float* weight = (const float*)d_in[2];
    const float* w_ih   = (const float*)d_in[3];
    // d_in[4] = w_hh: zero forward contribution (h0 = 0)
    const float* b_ih   = (const float*)d_in[5];
    const float* b_hh   = (const float*)d_in[6];
    float* out = (float*)d_out;

    const int n = in_sizes[0]/CDIM;   // 100000
    const int e = in_sizes[1]/2;      // 1600000
    const int* srcp = ei;
    const int* dstp = ei + e;

    auto alignup = [](size_t v){ return (v + 255) & ~(size_t)255; };
    char*  base = (char*)d_ws;
    size_t o = 0;
    short*  wfrag  = (short*) (base+o); o += alignup((size_t)CDIM*CDIM*sizeof(short));
    int*    deg    = (int*)   (base+o); o += alignup((size_t)n*4);          // | contiguous
    int*    spillc = (int*)   (base+o); o += alignup(256);                  // | zero region
    size_t  zbytes = (size_t)((char*)(base+o) - (char*)deg);
    int*    csr    = (int*)   (base+o); o += alignup((size_t)n*KCAP*4);     // 12.8 MB padded CSR
    bf16_t* aggbuf = (bf16_t*)(base+o); // n*CDIM*2 bytes  (~38.9 MB total: proven in R2)

    // d_out (51.2 MB) doubles as scratch until k_mgemm overwrites it last:
    //   [0, 25.6 MB)  : y0 = bf16(x)  (unscaled)
    //   [25.6, 38.4)  : spill list (int2) -- normally empty
    bf16_t* y0    = (bf16_t*)d_out;
    int2*   spill = (int2*)((char*)d_out + (size_t)n*CDIM*sizeof(bf16_t));

    const int nper  = (n + 7)/8;              // dst-range per XCD group
    const int castb = 512;                    // cast blocks (co-resident with edge blocks)
    const int edgeb = 1536;                   // 192 blocks per XCD group (multiple of 8)
    const int rb = (n + 3)/4;                 // k_agg: 4 waves (nodes) per block
    const int gw = (n + 15)/16;               // k_mgemm: 16-row stripes
    const int gb = (gw + 3)/4;

    k_lstm    <<<CDIM, CDIM, 0, stream>>>(weight, w_ih, b_ih, b_hh, wfrag,
                                          deg, (int)(zbytes/4));   // also zeroes deg+spillc
    k_fillcast<<<castb+edgeb, 256, 0, stream>>>(srcp, dstp, e, deg, csr, spill, spillc, nper,
                                                x, y0, n*CDIM/4, castb, edgeb);
    k_agg     <<<rb, 256, 0, stream>>>(y0, csr, deg, spill, spillc, aggbuf, n);
    k_mgemm   <<<gb, 256, 0, stream>>>(aggbuf, wfrag, out, n);
}